// Round 9
// baseline (373.863 us; speedup 1.0000x reference)
//
#include <hip/hip_runtime.h>
#include <math.h>

#define B_   32
#define T_   1024
#define IN_  512
#define HID_ 512
#define HYP_ 256
#define M_   (B_ * T_)   // 32768
#define R_   64          // rows per block -> 512 blocks, 2 blocks/CU

// LDS (exactly 80 KiB so 2 blocks/CU fit in 160 KiB):
//   H1S 32K | H2S 32K | STG 16K
// Phase-dead buffer plan:
//   P1: A(x) dbuf -> H2S+0/+4K; W even->STG, odd->H1S+0
//   P2: A=h1 (H1S resident); W even->STG, odd->H2S+0
//   P3 (per half): A(fc)=h2 (H2S resident); x dbuf -> H1S+0/+4K;
//                  W even->STG, odd->H1S+16K
#define H1S  0
#define H2S  32768
#define STG  65536
#define LDS_BYTES 81920

typedef _Float16 half8_t __attribute__((ext_vector_type(8)));
typedef _Float16 half4_t __attribute__((ext_vector_type(4)));
typedef float    f32x4   __attribute__((ext_vector_type(4)));

typedef __attribute__((address_space(1))) const void* gptr_as1;
typedef __attribute__((address_space(3))) void*       lptr_as3;

__device__ __forceinline__ void gload_lds16(const void* g, void* l) {
    __builtin_amdgcn_global_load_lds((gptr_as1)g, (lptr_as3)l, 16, 0, 0);
}

// counted-vmcnt (T4): manual vmcnt counts ONLY the W gload_lds (2/thread/step).
// x staging uses normal loads whose waits the compiler tracks separately
// inside the MFMA region (asm memory clobber prevents hoisting them above).
#define VMCNT2() asm volatile("s_waitcnt vmcnt(2)" ::: "memory")
#define VMCNT0() asm volatile("s_waitcnt vmcnt(0)" ::: "memory")
#define LGKM0()  asm volatile("s_waitcnt lgkmcnt(0)" ::: "memory")
#define SBAR()   __builtin_amdgcn_s_barrier()
#define SCHED0() __builtin_amdgcn_sched_barrier(0)

// ---------------------------------------------------------------------------
// fp32 -> fp16 weights only (~1.3 MB). 2048 elems/block.
// Ws 131072 | Wm 65536 | We 131072 | W2 262144 -> 64|32|64|128 blocks.
// ---------------------------------------------------------------------------
__global__ __launch_bounds__(256) void cvt_w(
    const float* __restrict__ Ws, _Float16* __restrict__ wsh,
    const float* __restrict__ Wm, _Float16* __restrict__ wmh,
    const float* __restrict__ We, _Float16* __restrict__ weh,
    const float* __restrict__ W2, _Float16* __restrict__ w2h)
{
    const int blk = blockIdx.x;
    const float* src; _Float16* dst; int base;
    if      (blk < 64)  { src = Ws; dst = wsh; base = blk; }
    else if (blk < 96)  { src = Wm; dst = wmh; base = blk - 64; }
    else if (blk < 160) { src = We; dst = weh; base = blk - 96; }
    else                { src = W2; dst = w2h; base = blk - 160; }
    const int i = base * 2048 + threadIdx.x * 8;
    f32x4 v0 = *(const f32x4*)(src + i);
    f32x4 v1 = *(const f32x4*)(src + i + 4);
    half8_t h;
    h[0] = (_Float16)v0[0]; h[1] = (_Float16)v0[1];
    h[2] = (_Float16)v0[2]; h[3] = (_Float16)v0[3];
    h[4] = (_Float16)v1[0]; h[5] = (_Float16)v1[1];
    h[6] = (_Float16)v1[2]; h[7] = (_Float16)v1[3];
    *(half8_t*)(dst + i) = h;
}

// ---------------------------------------------------------------------------
// Fragment-order + XOR-swizzled staging of a 256-row x 32-half W tile
// (16 KiB), 512 threads, 2 gload_lds/thread. Slot s: g=s>>6, c2=(s>>4)&3,
// holds source row g*16+((s&15)^c2), k-bytes [c2*16,c2*16+16). Source address
// carries the permutation; LDS dest linear (both-sides-or-neither).
// ---------------------------------------------------------------------------
__device__ __forceinline__ void stage512(const _Float16* src, int K,
                                         char* ldsbase, int tid)
{
#pragma unroll
    for (int q = 0; q < 2; ++q) {
        const int s = q * 512 + tid;
        const int g = s >> 6, c2 = (s >> 4) & 3, r = (s & 15) ^ c2;
        const char* gp = (const char*)src + (size_t)(g * 16 + r) * (K * 2) + c2 * 16;
        char* lp = ldsbase + (q * 512 + (tid & ~63)) * 16;
        gload_lds16(gp, lp);
    }
}

// ---------------------------------------------------------------------------
// x chunk staging: 64 rows x 32 halfs (4 KiB) from fp32 HBM, VALU convert,
// swizzled ds_write_b64. Normal loads -> compiler inserts the exact waitcnt.
// ---------------------------------------------------------------------------
__device__ __forceinline__ void stage_x(const float* __restrict__ x, int m0,
                                        int ks, char* dst, int tid)
{
    const int row = tid >> 3;            // 0..63
    const int k   = (tid & 7) * 4;       // 0..28 within the 32-half chunk
    f32x4 v = *(const f32x4*)(x + (size_t)(m0 + row) * IN_ + ks + k);
    half4_t h;
    h[0] = (_Float16)v[0]; h[1] = (_Float16)v[1];
    h[2] = (_Float16)v[2]; h[3] = (_Float16)v[3];
    const int c2 = k >> 3;
    *(half4_t*)(dst + (row >> 4) * 1024 + c2 * 256 +
                (((row & 15) ^ c2)) * 16 + (k & 7) * 2) = h;
}

// one k-step: 2 A-frags (wm) x 4 B-frags (wn) = 8 MFMAs
__device__ __forceinline__ void do_step8(const char* ab, const char* bb,
                                         int wm, int wn, int lsw,
                                         f32x4 acc[2][4])
{
    half8_t a0 = *(const half8_t*)(ab + (wm * 2 + 0) * 1024 + lsw);
    half8_t a1 = *(const half8_t*)(ab + (wm * 2 + 1) * 1024 + lsw);
#pragma unroll
    for (int j = 0; j < 4; ++j) {
        half8_t wf = *(const half8_t*)(bb + (wn * 4 + j) * 1024 + lsw);
        acc[0][j] = __builtin_amdgcn_mfma_f32_16x16x32_f16(a0, wf, acc[0][j], 0, 0, 0);
        acc[1][j] = __builtin_amdgcn_mfma_f32_16x16x32_f16(a1, wf, acc[1][j], 0, 0, 0);
    }
}

// bias+relu epilogue: scatter fp16 into XOR-swizzled fragment-order LDS
// (A-layout for next phase; k-chunk stride 4096 B at R_=64).
__device__ __forceinline__ void epi_relu_lds(char* dst, const f32x4 acc[2][4],
                                             const float* __restrict__ bias,
                                             int wm, int wn, int lq, int lr)
{
#pragma unroll
    for (int j = 0; j < 4; ++j) {
        const int col = wn * 64 + j * 16 + lr;
        const float bv = bias[col];
        const int cc2 = (col & 31) >> 3;
        const int cpart = (col >> 5) * 4096 + cc2 * 256 + (col & 7) * 2;
#pragma unroll
        for (int i = 0; i < 2; ++i) {
#pragma unroll
            for (int rg = 0; rg < 4; ++rg) {
                const int row = wm * 32 + i * 16 + lq * 4 + rg;
                const float v = fmaxf(acc[i][j][rg] + bv, 0.f);
                *(_Float16*)(dst + cpart + (row >> 4) * 1024 +
                             (((row & 15) ^ cc2)) * 16) = (_Float16)v;
            }
        }
    }
}

// ---------------------------------------------------------------------------
// Fused MLP v3: 512 blocks x 512 thr, R=64, LDS 80K -> 2 blocks/CU.
//   P1: h1 = relu(x@Ws^T+bs)   K=512, 16 steps (x fp32 reg-cvt + Ws gload)
//   P2: h2 = relu(h1@Wm^T+bm)  K=256,  8 steps
//   P3 per 256-col half: fc (8 steps, A=h2) then sig (16 steps, A=x reg-cvt)
//        -> bh(fp16) = (fc+be)*sigmoid(sig+b2)
// Steady step: stage W(t+1); vmcnt(2); bar; [stage_x(t+1) | 8 MFMA]; lgkm0; bar.
// ---------------------------------------------------------------------------
__global__ __launch_bounds__(512, 4) void fused_mlp(
    const float* __restrict__ x,
    const _Float16* __restrict__ wsh, const float* __restrict__ bs,
    const _Float16* __restrict__ wmh, const float* __restrict__ bm,
    const _Float16* __restrict__ weh, const float* __restrict__ be,
    const _Float16* __restrict__ w2h, const float* __restrict__ b2,
    _Float16* __restrict__ bh)
{
    __shared__ __align__(16) char lds[LDS_BYTES];

    const int tid  = threadIdx.x;
    const int m0   = blockIdx.x * R_;
    const int lane = tid & 63;
    const int wave = tid >> 6;
    const int wm = wave >> 2;        // 0..1 (m, 32 rows)
    const int wn = wave & 3;         // 0..3 (n, 64 cols)
    const int lq = lane >> 4, lr = lane & 15;
    const int lsw = (lane ^ ((lane >> 4) & 3)) * 16;

    const f32x4 zero = {0.f, 0.f, 0.f, 0.f};

    // ---- P1: h1 = relu(x @ Ws^T + bs), K=512, 16 steps ----
    {
        f32x4 acc[2][4];
#pragma unroll
        for (int i = 0; i < 2; ++i)
#pragma unroll
            for (int j = 0; j < 4; ++j) acc[i][j] = zero;

        stage512(wsh, IN_, lds + STG, tid);      // W(0) even -> STG
        stage_x(x, m0, 0, lds + H2S, tid);       // x(0) -> H2S slot0
        __syncthreads();                         // drains vm+lgkm

        for (int s = 0; s < 15; ++s) {
            const int e = s + 1;
            stage512(wsh + e * 32, IN_, (e & 1) ? lds + H1S : lds + STG, tid);
            VMCNT2(); SCHED0(); SBAR(); SCHED0();
            stage_x(x, m0, e * 32, lds + H2S + (e & 1) * 4096, tid);
            __builtin_amdgcn_s_setprio(1);
            do_step8(lds + H2S + (s & 1) * 4096,
                     (s & 1) ? lds + H1S : lds + STG, wm, wn, lsw, acc);
            __builtin_amdgcn_s_setprio(0);
            LGKM0(); SCHED0(); SBAR(); SCHED0();
        }
        VMCNT0(); SCHED0(); SBAR(); SCHED0();
        do_step8(lds + H2S + 4096, lds + H1S, wm, wn, lsw, acc);  // s=15 odd
        __syncthreads();
        stage512(wmh, HYP_, lds + STG, tid);     // P2 W(0); drained by next sync
        epi_relu_lds(lds + H1S, acc, bs, wm, wn, lq, lr);
        __syncthreads();
    }

    // ---- P2: h2 = relu(h1 @ Wm^T + bm), K=256, 8 steps ----
    {
        f32x4 acc[2][4];
#pragma unroll
        for (int i = 0; i < 2; ++i)
#pragma unroll
            for (int j = 0; j < 4; ++j) acc[i][j] = zero;

        for (int s = 0; s < 7; ++s) {
            const int e = s + 1;
            stage512(wmh + e * 32, HYP_, (e & 1) ? lds + H2S : lds + STG, tid);
            VMCNT2(); SCHED0(); SBAR(); SCHED0();
            __builtin_amdgcn_s_setprio(1);
            do_step8(lds + H1S + s * 4096,
                     (s & 1) ? lds + H2S : lds + STG, wm, wn, lsw, acc);
            __builtin_amdgcn_s_setprio(0);
            SCHED0(); SBAR(); SCHED0();
        }
        VMCNT0(); SCHED0(); SBAR(); SCHED0();
        do_step8(lds + H1S + 7 * 4096, lds + H2S, wm, wn, lsw, acc); // s=7 odd
        __syncthreads();
        epi_relu_lds(lds + H2S, acc, bm, wm, wn, lq, lr);
        __syncthreads();
    }

    // ---- P3 per 256-col half: fc (8 steps) + sig (16 steps) ----
#pragma unroll 1
    for (int half = 0; half < 2; ++half) {
        const int c0 = half * 256;
        const _Float16* wehh = weh + (size_t)c0 * HYP_;
        const _Float16* w2hh = w2h + (size_t)c0 * IN_;
        f32x4 accf[2][4], accs[2][4];
#pragma unroll
        for (int i = 0; i < 2; ++i)
#pragma unroll
            for (int j = 0; j < 4; ++j) { accf[i][j] = zero; accs[i][j] = zero; }

        stage512(wehh, HYP_, lds + STG, tid);    // fc W(0) even -> STG
        for (int s = 0; s < 7; ++s) {            // fc steps 0..6
            const int e = s + 1;
            stage512(wehh + e * 32, HYP_, (e & 1) ? lds + H1S + 16384 : lds + STG, tid);
            VMCNT2(); SCHED0(); SBAR(); SCHED0();
            __builtin_amdgcn_s_setprio(1);
            do_step8(lds + H2S + s * 4096,
                     (s & 1) ? lds + H1S + 16384 : lds + STG, wm, wn, lsw, accf);
            __builtin_amdgcn_s_setprio(0);
            SCHED0(); SBAR(); SCHED0();
        }
        {   // fc s=7: stage sig W(0) even->STG + x(0)->H1S slot0
            stage512(w2hh, IN_, lds + STG, tid);
            VMCNT2(); SCHED0(); SBAR(); SCHED0();
            stage_x(x, m0, 0, lds + H1S, tid);
            __builtin_amdgcn_s_setprio(1);
            do_step8(lds + H2S + 7 * 4096, lds + H1S + 16384, wm, wn, lsw, accf);
            __builtin_amdgcn_s_setprio(0);
            LGKM0(); SCHED0(); SBAR(); SCHED0();
        }
        for (int ts = 0; ts < 15; ++ts) {        // sig steps 0..14
            const int e = ts + 1;
            stage512(w2hh + e * 32, IN_, (e & 1) ? lds + H1S + 16384 : lds + STG, tid);
            VMCNT2(); SCHED0(); SBAR(); SCHED0();
            stage_x(x, m0, e * 32, lds + H1S + (e & 1) * 4096, tid);
            __builtin_amdgcn_s_setprio(1);
            do_step8(lds + H1S + (ts & 1) * 4096,
                     (ts & 1) ? lds + H1S + 16384 : lds + STG, wm, wn, lsw, accs);
            __builtin_amdgcn_s_setprio(0);
            LGKM0(); SCHED0(); SBAR(); SCHED0();
        }
        VMCNT0(); SCHED0(); SBAR(); SCHED0();
        do_step8(lds + H1S + 4096, lds + H1S + 16384, wm, wn, lsw, accs); // ts=15
        __syncthreads();

        // epilogue: bh(fp16) = (fc + be) * sigmoid(sig + b2)
#pragma unroll
        for (int j = 0; j < 4; ++j) {
            const int gcol = c0 + wn * 64 + j * 16 + lr;
            const float bev = be[gcol];
            const float b2v = b2[gcol];
#pragma unroll
            for (int i = 0; i < 2; ++i) {
#pragma unroll
                for (int rg = 0; rg < 4; ++rg) {
                    const int row = m0 + wm * 32 + i * 16 + lq * 4 + rg;
                    const float fc = accf[i][j][rg] + bev;
                    float sg = accs[i][j][rg] + b2v;
                    sg = 1.f / (1.f + __expf(-sg));
                    bh[(size_t)row * HID_ + gcol] = (_Float16)(fc * sg);
                }
            }
        }
        __syncthreads();
    }
}

// ---------------------------------------------------------------------------
// Scan: 16384 independent diagonal chains (chain r of batch b touches
// (t, (r+t)&511)). Reads fp16 b, writes fp32 outputs. 64-deep prefetch.
// ---------------------------------------------------------------------------
__global__ __launch_bounds__(64) void srnn_chain(const float* __restrict__ hidden,
                                                 const _Float16* __restrict__ bh,
                                                 float* __restrict__ out,
                                                 float* __restrict__ hlast)
{
    const int g = blockIdx.x * 64 + threadIdx.x;
    const int b = g >> 9;
    const int r = g & 511;
    const _Float16* bb = bh + (size_t)b * (T_ * HID_);
    float* ob = out + (size_t)b * (T_ * HID_);

    float c = hidden[b * HID_ + ((r + 511) & 511)];   // h_{-1}[(r-1) mod 512]

    float buf[64];
#pragma unroll
    for (int u = 0; u < 64; ++u)
        buf[u] = (float)bb[u * 512 + ((r + u) & 511)];

    for (int tb = 0; tb < T_; tb += 64) {
#pragma unroll
        for (int u = 0; u < 64; ++u) {
            const int t = tb + u;
            c = fmaxf(c + buf[u], 0.f);
            ob[t * 512 + ((r + t) & 511)] = c;
            const int tn = t + 64;
            if (tn < T_)
                buf[u] = (float)bb[tn * 512 + ((r + tn) & 511)];
        }
    }
    hlast[b * HID_ + ((r + 1023) & 511)] = c;
}

extern "C" void kernel_launch(void* const* d_in, const int* in_sizes, int n_in,
                              void* d_out, int out_size, void* d_ws, size_t ws_size,
                              hipStream_t stream)
{
    const float* x      = (const float*)d_in[0];  // [B,T,IN]
    const float* hidden = (const float*)d_in[1];  // [B,HID]
    const float* Ws     = (const float*)d_in[2];  // [HYP,IN]
    const float* bs     = (const float*)d_in[3];
    const float* Wm     = (const float*)d_in[4];  // [HYP,HYP]
    const float* bm     = (const float*)d_in[5];
    const float* We     = (const float*)d_in[6];  // [HID,HYP]
    const float* be     = (const float*)d_in[7];
    const float* W2     = (const float*)d_in[8];  // [HID,IN]
    const float* b2     = (const float*)d_in[9];

    float* outputs = (float*)d_out;                 // [B,T,HID]
    float* hlast   = outputs + (size_t)M_ * HID_;   // [B,HID]

    // workspace: bh fp16 [M,HID] 32MB | fp16 weights ~1.3MB
    _Float16* bh  = (_Float16*)d_ws;
    _Float16* wsh = bh + (size_t)M_ * HID_;         // [HYP,IN]
    _Float16* wmh = wsh + HYP_ * IN_;               // [HYP,HYP]
    _Float16* weh = wmh + HYP_ * HYP_;              // [HID,HYP]
    _Float16* w2h = weh + HID_ * HYP_;              // [HID,IN]

    cvt_w<<<dim3(288), 256, 0, stream>>>(Ws, wsh, Wm, wmh, We, weh, W2, w2h);
    fused_mlp<<<dim3(M_ / R_), 512, 0, stream>>>(
        x, wsh, bs, wmh, bm, weh, be, w2h, b2, bh);
    srnn_chain<<<dim3((B_ * HID_) / 64), dim3(64), 0, stream>>>(
        hidden, bh, outputs, hlast);
}

// Round 10
// 334.353 us; speedup vs baseline: 1.1182x; 1.1182x over previous
//
#include <hip/hip_runtime.h>
#include <math.h>

#define B_   32
#define T_   1024
#define IN_  512
#define HID_ 512
#define HYP_ 256
#define M_   (B_ * T_)   // 32768
#define R_   128         // rows per fused block -> 256 blocks = 1/CU, one round

// LDS map (bytes): h1s 64K | h2s 64K | stg 16K = 144 KiB
// Stage dbufs live in phase-dead regions:
//  P1: A(xh)-> H2S+0/+8K, W-odd -> H1S+0 (epi overwrites H1S after)
//  P2: W-odd -> H2S+0 (A-chunks dead; epi overwrites H2S after)
//  P3/4: xh -> H1S+0/+8K, W-odd -> H1S+16K (H1S dead after P2)
#define H1S  0
#define H2S  65536
#define STG  131072
#define LDS_BYTES 147456

typedef _Float16 half8_t __attribute__((ext_vector_type(8)));
typedef float    f32x4   __attribute__((ext_vector_type(4)));

typedef __attribute__((address_space(1))) const void* gptr_as1;
typedef __attribute__((address_space(3))) void*       lptr_as3;

__device__ __forceinline__ void gload_lds16(const void* g, void* l) {
    __builtin_amdgcn_global_load_lds((gptr_as1)g, (lptr_as3)l, 16, 0, 0);
}

// counted-vmcnt pipeline (T4): literal = loads just issued for tile t+1;
// waits tile t complete while t+1 stays in flight.
#define VMCNT3() asm volatile("s_waitcnt vmcnt(3)" ::: "memory")
#define VMCNT2() asm volatile("s_waitcnt vmcnt(2)" ::: "memory")
#define VMCNT0() asm volatile("s_waitcnt vmcnt(0)" ::: "memory")
#define SBAR()   __builtin_amdgcn_s_barrier()
#define SCHED0() __builtin_amdgcn_sched_barrier(0)

// ---------------------------------------------------------------------------
// fp32 -> fp16: x (8192 blocks) + Ws(64) + Wm(32) + We(64) + W2(128).
// ---------------------------------------------------------------------------
__global__ __launch_bounds__(256) void cvt_all(
    const float* __restrict__ x,  _Float16* __restrict__ xh,
    const float* __restrict__ Ws, _Float16* __restrict__ wsh,
    const float* __restrict__ Wm, _Float16* __restrict__ wmh,
    const float* __restrict__ We, _Float16* __restrict__ weh,
    const float* __restrict__ W2, _Float16* __restrict__ w2h)
{
    const int blk = blockIdx.x;
    const float* src; _Float16* dst; int base;
    if      (blk < 8192) { src = x;  dst = xh;  base = blk; }
    else if (blk < 8256) { src = Ws; dst = wsh; base = blk - 8192; }
    else if (blk < 8288) { src = Wm; dst = wmh; base = blk - 8256; }
    else if (blk < 8352) { src = We; dst = weh; base = blk - 8288; }
    else                 { src = W2; dst = w2h; base = blk - 8352; }
    const int i = base * 2048 + threadIdx.x * 8;
    f32x4 v0 = *(const f32x4*)(src + i);
    f32x4 v1 = *(const f32x4*)(src + i + 4);
    half8_t h;
    h[0] = (_Float16)v0[0]; h[1] = (_Float16)v0[1];
    h[2] = (_Float16)v0[2]; h[3] = (_Float16)v0[3];
    h[4] = (_Float16)v1[0]; h[5] = (_Float16)v1[1];
    h[6] = (_Float16)v1[2]; h[7] = (_Float16)v1[3];
    *(half8_t*)(dst + i) = h;
}

// ---------------------------------------------------------------------------
// Fragment-order + XOR-swizzled staging. Slot s (16B): g=s>>6, c2=(s>>4)&3,
// rho=s&15 holds source row g*16+(rho^c2), k-bytes [c2*16,c2*16+16). Read side
// compensates via lsw. Source carries the permutation; LDS dest linear.
// stage512: 256-row x 32-half W tile (16 KiB), 2 loads/thread (512 thr).
// stageA:   128-row x 32-half A chunk (8 KiB), 1 load/thread.
// ---------------------------------------------------------------------------
__device__ __forceinline__ void stage512(const _Float16* src, int K,
                                         char* ldsbase, int tid)
{
#pragma unroll
    for (int q = 0; q < 2; ++q) {
        const int s = q * 512 + tid;
        const int g = s >> 6, c2 = (s >> 4) & 3, r = (s & 15) ^ c2;
        const char* gp = (const char*)src + (size_t)(g * 16 + r) * (K * 2) + c2 * 16;
        char* lp = ldsbase + (q * 512 + (tid & ~63)) * 16;
        gload_lds16(gp, lp);
    }
}

__device__ __forceinline__ void stageA(const _Float16* src, int K,
                                       char* ldsbase, int tid)
{
    const int s = tid;                       // 0..511 -> 8 frags
    const int g = s >> 6, c2 = (s >> 4) & 3, r = (s & 15) ^ c2;
    const char* gp = (const char*)src + (size_t)(g * 16 + r) * (K * 2) + c2 * 16;
    char* lp = ldsbase + (tid & ~63) * 16;
    gload_lds16(gp, lp);
}

// one k-step: 4 A-frags (wm) x 4 B-frags (wn) = 16 MFMAs
__device__ __forceinline__ void do_step16(const char* ab, const char* bb,
                                          int wm, int wn, int lsw,
                                          f32x4 acc[4][4])
{
    half8_t af[4], wf[4];
#pragma unroll
    for (int i = 0; i < 4; ++i)
        af[i] = *(const half8_t*)(ab + (wm * 4 + i) * 1024 + lsw);
#pragma unroll
    for (int j = 0; j < 4; ++j)
        wf[j] = *(const half8_t*)(bb + (wn * 4 + j) * 1024 + lsw);
#pragma unroll
    for (int i = 0; i < 4; ++i)
#pragma unroll
        for (int j = 0; j < 4; ++j)
            acc[i][j] = __builtin_amdgcn_mfma_f32_16x16x32_f16(af[i], wf[j], acc[i][j], 0, 0, 0);
}

// bias+relu epilogue: scatter fp16 into XOR-swizzled fragment-order LDS
// (A-layout for the next phase; k-chunk stride 8192 B for R_=128).
__device__ __forceinline__ void epi_relu_lds(char* dst, const f32x4 acc[4][4],
                                             const float* __restrict__ bias,
                                             int wm, int wn, int lq, int lr)
{
#pragma unroll
    for (int j = 0; j < 4; ++j) {
        const int col = wn * 64 + j * 16 + lr;
        const float bv = bias[col];
        const int cc2 = (col & 31) >> 3;
        const int cpart = (col >> 5) * 8192 + cc2 * 256 + (col & 7) * 2;
#pragma unroll
        for (int i = 0; i < 4; ++i) {
#pragma unroll
            for (int rg = 0; rg < 4; ++rg) {
                const int row = wm * 64 + i * 16 + lq * 4 + rg;
                const float v = fmaxf(acc[i][j][rg] + bv, 0.f);
                *(_Float16*)(dst + cpart + (row >> 4) * 1024 +
                             (((row & 15) ^ cc2)) * 16) = (_Float16)v;
            }
        }
    }
}

// ---------------------------------------------------------------------------
// Fused MLP (round-8 proven structure): 256 blocks x 512 threads, R=128.
//   P1: h1 = relu(xh@Ws^T+bs)   K=512, 16 steps (stage xh 8K + Ws 16K)
//   P2: h2 = relu(h1@Wm^T+bm)   K=256,  8 steps (stage Wm 16K; A=H1S)
//   P3/4 per 256-col half: fc (8 steps, A=H2S) then sig (16 steps, A=xh
//        streamed again) -> bh(fp16) = (fc+be)*sigmoid(sig+b2)
// Steady step: stage(t+1); vmcnt(L); bar; 16 MFMA (setprio); bar.
// ---------------------------------------------------------------------------
__global__ __launch_bounds__(512, 2) void fused_mlp(
    const _Float16* __restrict__ xh,
    const _Float16* __restrict__ wsh, const float* __restrict__ bs,
    const _Float16* __restrict__ wmh, const float* __restrict__ bm,
    const _Float16* __restrict__ weh, const float* __restrict__ be,
    const _Float16* __restrict__ w2h, const float* __restrict__ b2,
    _Float16* __restrict__ bh)
{
    __shared__ __align__(16) char lds[LDS_BYTES];

    const int tid  = threadIdx.x;
    const int m0   = blockIdx.x * R_;
    const int lane = tid & 63;
    const int wave = tid >> 6;
    const int wm = wave >> 2;        // 0..1 (m, 64 rows each)
    const int wn = wave & 3;         // 0..3 (n, 64 cols each)
    const int lq = lane >> 4, lr = lane & 15;
    const int lsw = (lane ^ ((lane >> 4) & 3)) * 16;

    const _Float16* xrow = xh + (size_t)m0 * IN_;
    const f32x4 zero = {0.f, 0.f, 0.f, 0.f};

    // ---- P1: h1 = relu(xh @ Ws^T + bs), K=512, 16 steps ----
    {
        f32x4 acc[4][4];
#pragma unroll
        for (int i = 0; i < 4; ++i)
#pragma unroll
            for (int j = 0; j < 4; ++j) acc[i][j] = zero;

        stageA(xrow, IN_, lds + H2S, tid);
        stage512(wsh, IN_, lds + STG, tid);
        for (int s = 0; s < 15; ++s) {
            const int e = s + 1;
            stageA(xrow + e * 32, IN_, lds + H2S + (e & 1) * 8192, tid);
            stage512(wsh + e * 32, IN_, (e & 1) ? lds + H1S : lds + STG, tid);
            VMCNT3(); SCHED0(); SBAR(); SCHED0();
            const char* ab = lds + H2S + (s & 1) * 8192;
            const char* bb = (s & 1) ? lds + H1S : lds + STG;
            __builtin_amdgcn_s_setprio(1);
            do_step16(ab, bb, wm, wn, lsw, acc);
            __builtin_amdgcn_s_setprio(0);
            SCHED0(); SBAR(); SCHED0();
        }
        VMCNT0(); SCHED0(); SBAR(); SCHED0();
        do_step16(lds + H2S + 8192, lds + H1S, wm, wn, lsw, acc);  // s=15 (odd)
        __syncthreads();
        epi_relu_lds(lds + H1S, acc, bs, wm, wn, lq, lr);
        __syncthreads();
    }

    // ---- P2: h2 = relu(h1 @ Wm^T + bm), K=256, 8 steps ----
    {
        f32x4 acc[4][4];
#pragma unroll
        for (int i = 0; i < 4; ++i)
#pragma unroll
            for (int j = 0; j < 4; ++j) acc[i][j] = zero;

        stage512(wmh, HYP_, lds + STG, tid);
        for (int s = 0; s < 7; ++s) {
            const int e = s + 1;
            stage512(wmh + e * 32, HYP_, (e & 1) ? lds + H2S : lds + STG, tid);
            VMCNT2(); SCHED0(); SBAR(); SCHED0();
            const char* ab = lds + H1S + s * 8192;
            const char* bb = (s & 1) ? lds + H2S : lds + STG;
            __builtin_amdgcn_s_setprio(1);
            do_step16(ab, bb, wm, wn, lsw, acc);
            __builtin_amdgcn_s_setprio(0);
            SCHED0(); SBAR(); SCHED0();
        }
        VMCNT0(); SCHED0(); SBAR(); SCHED0();
        do_step16(lds + H1S + 7 * 8192, lds + H2S, wm, wn, lsw, acc); // s=7 (odd)
        __syncthreads();
        epi_relu_lds(lds + H2S, acc, bm, wm, wn, lq, lr);
        __syncthreads();
    }

    // ---- P3/P4 per 256-col half: fc (8) + sig (16) pipelined steps ----
#pragma unroll 1
    for (int half = 0; half < 2; ++half) {
        const int c0 = half * 256;
        const _Float16* wehh = weh + (size_t)c0 * HYP_;
        const _Float16* w2hh = w2h + (size_t)c0 * IN_;
        f32x4 accf[4][4], accs[4][4];
#pragma unroll
        for (int i = 0; i < 4; ++i)
#pragma unroll
            for (int j = 0; j < 4; ++j) { accf[i][j] = zero; accs[i][j] = zero; }

        stage512(wehh, HYP_, lds + STG, tid);          // fc tile 0 (even)
        for (int s = 0; s < 7; ++s) {                  // stage fc tiles 1..7
            const int e = s + 1;
            stage512(wehh + e * 32, HYP_, (e & 1) ? lds + H1S + 16384 : lds + STG, tid);
            VMCNT2(); SCHED0(); SBAR(); SCHED0();
            const char* ab = lds + H2S + s * 8192;
            const char* bb = (s & 1) ? lds + H1S + 16384 : lds + STG;
            __builtin_amdgcn_s_setprio(1);
            do_step16(ab, bb, wm, wn, lsw, accf);
            __builtin_amdgcn_s_setprio(0);
            SCHED0(); SBAR(); SCHED0();
        }
        {   // s=7: stage sig tile e=8 (ts=0, even parity), compute fc tile 7
            stageA(xrow, IN_, lds + H1S, tid);
            stage512(w2hh, IN_, lds + STG, tid);
            VMCNT3(); SCHED0(); SBAR(); SCHED0();
            __builtin_amdgcn_s_setprio(1);
            do_step16(lds + H2S + 7 * 8192, lds + H1S + 16384, wm, wn, lsw, accf);
            __builtin_amdgcn_s_setprio(0);
            SCHED0(); SBAR(); SCHED0();
        }
        for (int s = 8; s < 23; ++s) {                 // stage sig tiles 1..15
            const int e = s + 1, ts = e - 8;
            stageA(xrow + ts * 32, IN_, lds + H1S + (e & 1) * 8192, tid);
            stage512(w2hh + ts * 32, IN_, (e & 1) ? lds + H1S + 16384 : lds + STG, tid);
            VMCNT3(); SCHED0(); SBAR(); SCHED0();
            const char* ab = lds + H1S + (s & 1) * 8192;
            const char* bb = (s & 1) ? lds + H1S + 16384 : lds + STG;
            __builtin_amdgcn_s_setprio(1);
            do_step16(ab, bb, wm, wn, lsw, accs);
            __builtin_amdgcn_s_setprio(0);
            SCHED0(); SBAR(); SCHED0();
        }
        VMCNT0(); SCHED0(); SBAR(); SCHED0();
        do_step16(lds + H1S + 8192, lds + H1S + 16384, wm, wn, lsw, accs); // s=23 (odd)
        __syncthreads();

        // epilogue: bh(fp16) = (fc + be) * sigmoid(sig + b2)
#pragma unroll
        for (int j = 0; j < 4; ++j) {
            const int gcol = c0 + wn * 64 + j * 16 + lr;
            const float bev = be[gcol];
            const float b2v = b2[gcol];
#pragma unroll
            for (int i = 0; i < 4; ++i) {
#pragma unroll
                for (int rg = 0; rg < 4; ++rg) {
                    const int row = m0 + wm * 64 + i * 16 + lq * 4 + rg;
                    const float fc = accf[i][j][rg] + bev;
                    float sg = accs[i][j][rg] + b2v;
                    sg = 1.f / (1.f + __expf(-sg));
                    bh[(size_t)row * HID_ + gcol] = (_Float16)(fc * sg);
                }
            }
        }
        __syncthreads();   // protect H1S/STG before half=1 restages
    }
}

// ---------------------------------------------------------------------------
// Scan: 16384 independent diagonal chains (chain r of batch b touches
// (t, (r+t)&511)). One thread/chain, 128-deep register prefetch.
// NOTE: bh/out deliberately NOT __restrict__ — may-aliasing pins the prefetch
// loads in program order (round 9's __restrict__ let the compiler sink all
// loads to their uses: VGPR 36, 271 us). In-flight = 128 loads x 128 B/wave
// x 256 waves = 4 MB, covering HBM latency at ~full read BW.
// ---------------------------------------------------------------------------
__global__ __launch_bounds__(64) void srnn_chain(const float* hidden,
                                                 const _Float16* bh,
                                                 float* out,
                                                 float* hlast)
{
    const int g = blockIdx.x * 64 + threadIdx.x;
    const int b = g >> 9;
    const int r = g & 511;
    const _Float16* bb = bh + (size_t)b * (T_ * HID_);
    float* ob = out + (size_t)b * (T_ * HID_);

    float c = hidden[b * HID_ + ((r + 511) & 511)];   // h_{-1}[(r-1) mod 512]

    float buf[128];
#pragma unroll
    for (int u = 0; u < 128; ++u)
        buf[u] = (float)bb[u * 512 + ((r + u) & 511)];

    for (int tb = 0; tb < T_; tb += 128) {
#pragma unroll
        for (int u = 0; u < 128; ++u) {
            const int t = tb + u;
            c = fmaxf(c + buf[u], 0.f);
            ob[t * 512 + ((r + t) & 511)] = c;
            const int tn = t + 128;
            if (tn < T_)   // uniform branch
                buf[u] = (float)bb[tn * 512 + ((r + tn) & 511)];
        }
    }
    hlast[b * HID_ + ((r + 1023) & 511)] = c;
}

extern "C" void kernel_launch(void* const* d_in, const int* in_sizes, int n_in,
                              void* d_out, int out_size, void* d_ws, size_t ws_size,
                              hipStream_t stream)
{
    const float* x      = (const float*)d_in[0];  // [B,T,IN]
    const float* hidden = (const float*)d_in[1];  // [B,HID]
    const float* Ws     = (const float*)d_in[2];  // [HYP,IN]
    const float* bs     = (const float*)d_in[3];
    const float* Wm     = (const float*)d_in[4];  // [HYP,HYP]
    const float* bm     = (const float*)d_in[5];
    const float* We     = (const float*)d_in[6];  // [HID,HYP]
    const float* be     = (const float*)d_in[7];
    const float* W2     = (const float*)d_in[8];  // [HID,IN]
    const float* b2     = (const float*)d_in[9];

    float* outputs = (float*)d_out;                 // [B,T,HID]
    float* hlast   = outputs + (size_t)M_ * HID_;   // [B,HID]

    // xh (32 MB fp16) lives in the FRONT of d_out: fused reads it for the
    // whole kernel; the scan overwrites the region afterwards (stream-ordered,
    // and every launch rewrites all of d_out -> deterministic).
    _Float16* xh = (_Float16*)d_out;                // [M,IN]

    // workspace: bh fp16 [M,HID] 32MB | fp16 weights ~1.3MB
    _Float16* bh  = (_Float16*)d_ws;
    _Float16* wsh = bh + (size_t)M_ * HID_;         // [HYP,IN]
    _Float16* wmh = wsh + HYP_ * IN_;               // [HYP,HYP]
    _Float16* weh = wmh + HYP_ * HYP_;              // [HID,HYP]
    _Float16* w2h = weh + HID_ * HYP_;              // [HID,IN]

    cvt_all<<<dim3(8480), 256, 0, stream>>>(x, xh, Ws, wsh, Wm, wmh, We, weh, W2, w2h);
    fused_mlp<<<dim3(M_ / R_), 512, 0, stream>>>(
        xh, wsh, bs, wmh, bm, weh, be, w2h, b2, bh);
    srnn_chain<<<dim3((B_ * HID_) / 64), dim3(64), 0, stream>>>(
        hidden, bh, outputs, hlast);
}

// Round 11
// 120.280 us; speedup vs baseline: 3.1083x; 2.7798x over previous
//
#include <hip/hip_runtime.h>
#include <math.h>

#define B_   32
#define T_   1024
#define IN_  512
#define HID_ 512
#define HYP_ 256
#define M_   (B_ * T_)   // 32768
#define R_   128         // rows per fused block -> 256 blocks = 1/CU
#define NSEG 8
#define SEGL 128         // T_/NSEG
#define NCH  (B_ * HID_) // 16384 chains

// LDS map (bytes): h1s 64K | h2s 64K | stg 16K = 144 KiB
#define H1S  0
#define H2S  65536
#define STG  131072
#define LDS_BYTES 147456

typedef _Float16 half8_t __attribute__((ext_vector_type(8)));
typedef float    f32x4   __attribute__((ext_vector_type(4)));

typedef __attribute__((address_space(1))) const void* gptr_as1;
typedef __attribute__((address_space(3))) void*       lptr_as3;

__device__ __forceinline__ void gload_lds16(const void* g, void* l) {
    __builtin_amdgcn_global_load_lds((gptr_as1)g, (lptr_as3)l, 16, 0, 0);
}

#define VMCNT3() asm volatile("s_waitcnt vmcnt(3)" ::: "memory")
#define VMCNT2() asm volatile("s_waitcnt vmcnt(2)" ::: "memory")
#define VMCNT0() asm volatile("s_waitcnt vmcnt(0)" ::: "memory")
#define SBAR()   __builtin_amdgcn_s_barrier()
#define SCHED0() __builtin_amdgcn_sched_barrier(0)

// ---------------------------------------------------------------------------
// fp32 -> fp16: x (8192 blocks) + Ws(64) + Wm(32) + We(64) + W2(128).
// ---------------------------------------------------------------------------
__global__ __launch_bounds__(256) void cvt_all(
    const float* __restrict__ x,  _Float16* __restrict__ xh,
    const float* __restrict__ Ws, _Float16* __restrict__ wsh,
    const float* __restrict__ Wm, _Float16* __restrict__ wmh,
    const float* __restrict__ We, _Float16* __restrict__ weh,
    const float* __restrict__ W2, _Float16* __restrict__ w2h)
{
    const int blk = blockIdx.x;
    const float* src; _Float16* dst; int base;
    if      (blk < 8192) { src = x;  dst = xh;  base = blk; }
    else if (blk < 8256) { src = Ws; dst = wsh; base = blk - 8192; }
    else if (blk < 8288) { src = Wm; dst = wmh; base = blk - 8256; }
    else if (blk < 8352) { src = We; dst = weh; base = blk - 8288; }
    else                 { src = W2; dst = w2h; base = blk - 8352; }
    const int i = base * 2048 + threadIdx.x * 8;
    f32x4 v0 = *(const f32x4*)(src + i);
    f32x4 v1 = *(const f32x4*)(src + i + 4);
    half8_t h;
    h[0] = (_Float16)v0[0]; h[1] = (_Float16)v0[1];
    h[2] = (_Float16)v0[2]; h[3] = (_Float16)v0[3];
    h[4] = (_Float16)v1[0]; h[5] = (_Float16)v1[1];
    h[6] = (_Float16)v1[2]; h[7] = (_Float16)v1[3];
    *(half8_t*)(dst + i) = h;
}

// ---------------------------------------------------------------------------
// Fragment-order + XOR-swizzled staging (proven r8 structure).
// ---------------------------------------------------------------------------
__device__ __forceinline__ void stage512(const _Float16* src, int K,
                                         char* ldsbase, int tid)
{
#pragma unroll
    for (int q = 0; q < 2; ++q) {
        const int s = q * 512 + tid;
        const int g = s >> 6, c2 = (s >> 4) & 3, r = (s & 15) ^ c2;
        const char* gp = (const char*)src + (size_t)(g * 16 + r) * (K * 2) + c2 * 16;
        char* lp = ldsbase + (q * 512 + (tid & ~63)) * 16;
        gload_lds16(gp, lp);
    }
}

__device__ __forceinline__ void stageA(const _Float16* src, int K,
                                       char* ldsbase, int tid)
{
    const int s = tid;
    const int g = s >> 6, c2 = (s >> 4) & 3, r = (s & 15) ^ c2;
    const char* gp = (const char*)src + (size_t)(g * 16 + r) * (K * 2) + c2 * 16;
    char* lp = ldsbase + (tid & ~63) * 16;
    gload_lds16(gp, lp);
}

__device__ __forceinline__ void do_step16(const char* ab, const char* bb,
                                          int wm, int wn, int lsw,
                                          f32x4 acc[4][4])
{
    half8_t af[4], wf[4];
#pragma unroll
    for (int i = 0; i < 4; ++i)
        af[i] = *(const half8_t*)(ab + (wm * 4 + i) * 1024 + lsw);
#pragma unroll
    for (int j = 0; j < 4; ++j)
        wf[j] = *(const half8_t*)(bb + (wn * 4 + j) * 1024 + lsw);
#pragma unroll
    for (int i = 0; i < 4; ++i)
#pragma unroll
        for (int j = 0; j < 4; ++j)
            acc[i][j] = __builtin_amdgcn_mfma_f32_16x16x32_f16(af[i], wf[j], acc[i][j], 0, 0, 0);
}

__device__ __forceinline__ void epi_relu_lds(char* dst, const f32x4 acc[4][4],
                                             const float* __restrict__ bias,
                                             int wm, int wn, int lq, int lr)
{
#pragma unroll
    for (int j = 0; j < 4; ++j) {
        const int col = wn * 64 + j * 16 + lr;
        const float bv = bias[col];
        const int cc2 = (col & 31) >> 3;
        const int cpart = (col >> 5) * 8192 + cc2 * 256 + (col & 7) * 2;
#pragma unroll
        for (int i = 0; i < 4; ++i) {
#pragma unroll
            for (int rg = 0; rg < 4; ++rg) {
                const int row = wm * 64 + i * 16 + lq * 4 + rg;
                const float v = fmaxf(acc[i][j][rg] + bv, 0.f);
                *(_Float16*)(dst + cpart + (row >> 4) * 1024 +
                             (((row & 15) ^ cc2)) * 16) = (_Float16)v;
            }
        }
    }
}

// ---------------------------------------------------------------------------
// Fused MLP (round-8 proven structure): 256 blocks x 512 threads, R=128.
// ---------------------------------------------------------------------------
__global__ __launch_bounds__(512, 2) void fused_mlp(
    const _Float16* __restrict__ xh,
    const _Float16* __restrict__ wsh, const float* __restrict__ bs,
    const _Float16* __restrict__ wmh, const float* __restrict__ bm,
    const _Float16* __restrict__ weh, const float* __restrict__ be,
    const _Float16* __restrict__ w2h, const float* __restrict__ b2,
    _Float16* __restrict__ bh)
{
    __shared__ __align__(16) char lds[LDS_BYTES];

    const int tid  = threadIdx.x;
    const int m0   = blockIdx.x * R_;
    const int lane = tid & 63;
    const int wave = tid >> 6;
    const int wm = wave >> 2;
    const int wn = wave & 3;
    const int lq = lane >> 4, lr = lane & 15;
    const int lsw = (lane ^ ((lane >> 4) & 3)) * 16;

    const _Float16* xrow = xh + (size_t)m0 * IN_;
    const f32x4 zero = {0.f, 0.f, 0.f, 0.f};

    // ---- P1: h1 = relu(xh @ Ws^T + bs), K=512, 16 steps ----
    {
        f32x4 acc[4][4];
#pragma unroll
        for (int i = 0; i < 4; ++i)
#pragma unroll
            for (int j = 0; j < 4; ++j) acc[i][j] = zero;

        stageA(xrow, IN_, lds + H2S, tid);
        stage512(wsh, IN_, lds + STG, tid);
        for (int s = 0; s < 15; ++s) {
            const int e = s + 1;
            stageA(xrow + e * 32, IN_, lds + H2S + (e & 1) * 8192, tid);
            stage512(wsh + e * 32, IN_, (e & 1) ? lds + H1S : lds + STG, tid);
            VMCNT3(); SCHED0(); SBAR(); SCHED0();
            const char* ab = lds + H2S + (s & 1) * 8192;
            const char* bb = (s & 1) ? lds + H1S : lds + STG;
            __builtin_amdgcn_s_setprio(1);
            do_step16(ab, bb, wm, wn, lsw, acc);
            __builtin_amdgcn_s_setprio(0);
            SCHED0(); SBAR(); SCHED0();
        }
        VMCNT0(); SCHED0(); SBAR(); SCHED0();
        do_step16(lds + H2S + 8192, lds + H1S, wm, wn, lsw, acc);
        __syncthreads();
        epi_relu_lds(lds + H1S, acc, bs, wm, wn, lq, lr);
        __syncthreads();
    }

    // ---- P2: h2 = relu(h1 @ Wm^T + bm), K=256, 8 steps ----
    {
        f32x4 acc[4][4];
#pragma unroll
        for (int i = 0; i < 4; ++i)
#pragma unroll
            for (int j = 0; j < 4; ++j) acc[i][j] = zero;

        stage512(wmh, HYP_, lds + STG, tid);
        for (int s = 0; s < 7; ++s) {
            const int e = s + 1;
            stage512(wmh + e * 32, HYP_, (e & 1) ? lds + H2S : lds + STG, tid);
            VMCNT2(); SCHED0(); SBAR(); SCHED0();
            const char* ab = lds + H1S + s * 8192;
            const char* bb = (s & 1) ? lds + H2S : lds + STG;
            __builtin_amdgcn_s_setprio(1);
            do_step16(ab, bb, wm, wn, lsw, acc);
            __builtin_amdgcn_s_setprio(0);
            SCHED0(); SBAR(); SCHED0();
        }
        VMCNT0(); SCHED0(); SBAR(); SCHED0();
        do_step16(lds + H1S + 7 * 8192, lds + H2S, wm, wn, lsw, acc);
        __syncthreads();
        epi_relu_lds(lds + H2S, acc, bm, wm, wn, lq, lr);
        __syncthreads();
    }

    // ---- P3/P4 per 256-col half: fc (8) + sig (16) pipelined steps ----
#pragma unroll 1
    for (int half = 0; half < 2; ++half) {
        const int c0 = half * 256;
        const _Float16* wehh = weh + (size_t)c0 * HYP_;
        const _Float16* w2hh = w2h + (size_t)c0 * IN_;
        f32x4 accf[4][4], accs[4][4];
#pragma unroll
        for (int i = 0; i < 4; ++i)
#pragma unroll
            for (int j = 0; j < 4; ++j) { accf[i][j] = zero; accs[i][j] = zero; }

        stage512(wehh, HYP_, lds + STG, tid);
        for (int s = 0; s < 7; ++s) {
            const int e = s + 1;
            stage512(wehh + e * 32, HYP_, (e & 1) ? lds + H1S + 16384 : lds + STG, tid);
            VMCNT2(); SCHED0(); SBAR(); SCHED0();
            const char* ab = lds + H2S + s * 8192;
            const char* bb = (s & 1) ? lds + H1S + 16384 : lds + STG;
            __builtin_amdgcn_s_setprio(1);
            do_step16(ab, bb, wm, wn, lsw, accf);
            __builtin_amdgcn_s_setprio(0);
            SCHED0(); SBAR(); SCHED0();
        }
        {
            stageA(xrow, IN_, lds + H1S, tid);
            stage512(w2hh, IN_, lds + STG, tid);
            VMCNT3(); SCHED0(); SBAR(); SCHED0();
            __builtin_amdgcn_s_setprio(1);
            do_step16(lds + H2S + 7 * 8192, lds + H1S + 16384, wm, wn, lsw, accf);
            __builtin_amdgcn_s_setprio(0);
            SCHED0(); SBAR(); SCHED0();
        }
        for (int s = 8; s < 23; ++s) {
            const int e = s + 1, ts = e - 8;
            stageA(xrow + ts * 32, IN_, lds + H1S + (e & 1) * 8192, tid);
            stage512(w2hh + ts * 32, IN_, (e & 1) ? lds + H1S + 16384 : lds + STG, tid);
            VMCNT3(); SCHED0(); SBAR(); SCHED0();
            const char* ab = lds + H1S + (s & 1) * 8192;
            const char* bb = (s & 1) ? lds + H1S + 16384 : lds + STG;
            __builtin_amdgcn_s_setprio(1);
            do_step16(ab, bb, wm, wn, lsw, accs);
            __builtin_amdgcn_s_setprio(0);
            SCHED0(); SBAR(); SCHED0();
        }
        VMCNT0(); SCHED0(); SBAR(); SCHED0();
        do_step16(lds + H1S + 8192, lds + H1S + 16384, wm, wn, lsw, accs);
        __syncthreads();

#pragma unroll
        for (int j = 0; j < 4; ++j) {
            const int gcol = c0 + wn * 64 + j * 16 + lr;
            const float bev = be[gcol];
            const float b2v = b2[gcol];
#pragma unroll
            for (int i = 0; i < 4; ++i) {
#pragma unroll
                for (int rg = 0; rg < 4; ++rg) {
                    const int row = m0 + wm * 64 + i * 16 + lq * 4 + rg;
                    const float fc = accf[i][j][rg] + bev;
                    float sg = accs[i][j][rg] + b2v;
                    sg = 1.f / (1.f + __expf(-sg));
                    bh[(size_t)row * HID_ + gcol] = (_Float16)(fc * sg);
                }
            }
        }
        __syncthreads();
    }
}

// ---------------------------------------------------------------------------
// Segmented max-plus scan. h' = relu(h + b) over a segment composes to
// h_out = max(h_in + S, D), with per-element update S += b; D = max(D + b, 0).
// (S,D) composition is associative -> 3-kernel scheme, 8 segments/chain:
//   A seg_reduce: (chain, seg) -> (S, D).         131072 thr (8 waves/CU)
//   B carry_scan: chain -> carries per segment + hlast.  16384 thr
//   C seg_apply:  (chain, seg) -> exact sequential recurrence from carry.
// Chain r of batch b touches (t, (r+t)&511); consecutive lanes r -> coalesced.
// ---------------------------------------------------------------------------
__global__ __launch_bounds__(256) void seg_reduce(const _Float16* __restrict__ bh,
                                                  float* __restrict__ Sarr,
                                                  float* __restrict__ Darr)
{
    const int G = blockIdx.x * 256 + threadIdx.x;   // 0..131071
    const int r = G & 511;
    const int seg = (G >> 9) & 7;
    const int b = G >> 12;
    const int chain = b * 512 + r;
    const _Float16* bb = bh + (size_t)b * (T_ * HID_);
    const int t0 = seg * SEGL;

    float S = 0.f, D = -__builtin_inff();
#pragma unroll 8
    for (int u = 0; u < SEGL; ++u) {
        const int t = t0 + u;
        const float v = (float)bb[t * 512 + ((r + t) & 511)];
        S += v;
        D = fmaxf(D + v, 0.f);
    }
    Sarr[seg * NCH + chain] = S;
    Darr[seg * NCH + chain] = D;
}

__global__ __launch_bounds__(64) void carry_scan(const float* __restrict__ hidden,
                                                 const float* __restrict__ Sarr,
                                                 const float* __restrict__ Darr,
                                                 float* __restrict__ carry,
                                                 float* __restrict__ hlast)
{
    const int chain = blockIdx.x * 64 + threadIdx.x;  // 0..16383
    const int b = chain >> 9, r = chain & 511;
    float c = hidden[b * 512 + ((r + 511) & 511)];    // h_{-1}[(r-1) mod 512]
#pragma unroll
    for (int j = 0; j < NSEG; ++j) {
        carry[j * NCH + chain] = c;
        c = fmaxf(c + Sarr[j * NCH + chain], Darr[j * NCH + chain]);
    }
    hlast[b * 512 + ((r + 1023) & 511)] = c;          // h_{T-1} position
}

__global__ __launch_bounds__(256) void seg_apply(const _Float16* __restrict__ bh,
                                                 const float* __restrict__ carry,
                                                 float* __restrict__ out)
{
    const int G = blockIdx.x * 256 + threadIdx.x;
    const int r = G & 511;
    const int seg = (G >> 9) & 7;
    const int b = G >> 12;
    const int chain = b * 512 + r;
    const _Float16* bb = bh + (size_t)b * (T_ * HID_);
    float* ob = out + (size_t)b * (T_ * HID_);
    const int t0 = seg * SEGL;

    float c = carry[seg * NCH + chain];
#pragma unroll 8
    for (int u = 0; u < SEGL; ++u) {
        const int t = t0 + u;
        const int idx = t * 512 + ((r + t) & 511);
        c = fmaxf(c + (float)bb[idx], 0.f);
        ob[idx] = c;
    }
}

extern "C" void kernel_launch(void* const* d_in, const int* in_sizes, int n_in,
                              void* d_out, int out_size, void* d_ws, size_t ws_size,
                              hipStream_t stream)
{
    const float* x      = (const float*)d_in[0];  // [B,T,IN]
    const float* hidden = (const float*)d_in[1];  // [B,HID]
    const float* Ws     = (const float*)d_in[2];  // [HYP,IN]
    const float* bs     = (const float*)d_in[3];
    const float* Wm     = (const float*)d_in[4];  // [HYP,HYP]
    const float* bm     = (const float*)d_in[5];
    const float* We     = (const float*)d_in[6];  // [HID,HYP]
    const float* be     = (const float*)d_in[7];
    const float* W2     = (const float*)d_in[8];  // [HID,IN]
    const float* b2     = (const float*)d_in[9];

    float* outputs = (float*)d_out;                 // [B,T,HID]
    float* hlast   = outputs + (size_t)M_ * HID_;   // [B,HID]

    // xh (32 MB fp16) in the FRONT of d_out: read by fused_mlp, dead before
    // seg_apply overwrites the region (stream-ordered, fully rewritten).
    _Float16* xh = (_Float16*)d_out;                // [M,IN]

    // workspace: bh 32MB | weights 1.3MB | S,D,carry 1.5MB
    _Float16* bh   = (_Float16*)d_ws;
    _Float16* wsh  = bh + (size_t)M_ * HID_;        // [HYP,IN]
    _Float16* wmh  = wsh + HYP_ * IN_;              // [HYP,HYP]
    _Float16* weh  = wmh + HYP_ * HYP_;             // [HID,HYP]
    _Float16* w2h  = weh + HID_ * HYP_;             // [HID,IN]
    float*    Sarr = (float*)(w2h + HID_ * IN_);    // [NSEG, NCH]
    float*    Darr = Sarr + NSEG * NCH;             // [NSEG, NCH]
    float*    carr = Darr + NSEG * NCH;             // [NSEG, NCH]

    cvt_all<<<dim3(8480), 256, 0, stream>>>(x, xh, Ws, wsh, Wm, wmh, We, weh, W2, w2h);
    fused_mlp<<<dim3(M_ / R_), 512, 0, stream>>>(
        xh, wsh, bs, wmh, bm, weh, be, w2h, b2, bh);
    seg_reduce<<<dim3((NCH * NSEG) / 256), 256, 0, stream>>>(bh, Sarr, Darr);
    carry_scan<<<dim3(NCH / 64), 64, 0, stream>>>(hidden, Sarr, Darr, carr, hlast);
    seg_apply<<<dim3((NCH * NSEG) / 256), 256, 0, stream>>>(bh, carr, outputs);
}

// Round 12
// 117.749 us; speedup vs baseline: 3.1751x; 1.0215x over previous
//
#include <hip/hip_runtime.h>
#include <math.h>

#define B_   32
#define T_   1024
#define IN_  512
#define HID_ 512
#define HYP_ 256
#define M_   (B_ * T_)   // 32768
#define R_   128         // rows per fused block -> 256 blocks = 1/CU
#define NSEG 8
#define SEGL 128         // T_/NSEG
#define NCH  (B_ * HID_) // 16384 chains

// LDS map (bytes): H1S 64K | H2S 64K | STG 32K = 160 KiB exactly.
// Stage buffers live in phase-dead regions (verified per phase):
//  P1: A(xh) dbuf -> H2S+0 / H2S+16K; W even->STG, odd->H2S+32K
//  P2: A=h1 (H1S resident); W even->STG, odd->H2S+0 (dead after P1)
//  P3 fc:  A=h2 (H2S resident); W even->STG, odd->H1S+0 (dead after P2)
//  P4 sig: A(xh) dbuf -> H1S+32K / H1S+48K; W even->STG, odd->H1S+0
#define H1S  0
#define H2S  65536
#define STG  131072
#define LDS_BYTES 163840

typedef _Float16 half8_t __attribute__((ext_vector_type(8)));
typedef float    f32x4   __attribute__((ext_vector_type(4)));

typedef __attribute__((address_space(1))) const void* gptr_as1;
typedef __attribute__((address_space(3))) void*       lptr_as3;

__device__ __forceinline__ void gload_lds16(const void* g, void* l) {
    __builtin_amdgcn_global_load_lds((gptr_as1)g, (lptr_as3)l, 16, 0, 0);
}

// counted-vmcnt (T4): literal = loads intentionally left in flight.
#define VMCNT6() asm volatile("s_waitcnt vmcnt(6)" ::: "memory")
#define VMCNT4() asm volatile("s_waitcnt vmcnt(4)" ::: "memory")
#define VMCNT0() asm volatile("s_waitcnt vmcnt(0)" ::: "memory")
#define SBAR()   __builtin_amdgcn_s_barrier()
#define SCHED0() __builtin_amdgcn_sched_barrier(0)

// ---------------------------------------------------------------------------
// fp32 -> fp16: x (8192 blocks) + Ws(64) + Wm(32) + We(64) + W2(128).
// ---------------------------------------------------------------------------
__global__ __launch_bounds__(256) void cvt_all(
    const float* __restrict__ x,  _Float16* __restrict__ xh,
    const float* __restrict__ Ws, _Float16* __restrict__ wsh,
    const float* __restrict__ Wm, _Float16* __restrict__ wmh,
    const float* __restrict__ We, _Float16* __restrict__ weh,
    const float* __restrict__ W2, _Float16* __restrict__ w2h)
{
    const int blk = blockIdx.x;
    const float* src; _Float16* dst; int base;
    if      (blk < 8192) { src = x;  dst = xh;  base = blk; }
    else if (blk < 8256) { src = Ws; dst = wsh; base = blk - 8192; }
    else if (blk < 8288) { src = Wm; dst = wmh; base = blk - 8256; }
    else if (blk < 8352) { src = We; dst = weh; base = blk - 8288; }
    else                 { src = W2; dst = w2h; base = blk - 8352; }
    const int i = base * 2048 + threadIdx.x * 8;
    f32x4 v0 = *(const f32x4*)(src + i);
    f32x4 v1 = *(const f32x4*)(src + i + 4);
    half8_t h;
    h[0] = (_Float16)v0[0]; h[1] = (_Float16)v0[1];
    h[2] = (_Float16)v0[2]; h[3] = (_Float16)v0[3];
    h[4] = (_Float16)v1[0]; h[5] = (_Float16)v1[1];
    h[6] = (_Float16)v1[2]; h[7] = (_Float16)v1[3];
    *(half8_t*)(dst + i) = h;
}

// ---------------------------------------------------------------------------
// Fragment-order + XOR-swizzled staging (proven r8 layout).
// stage512: 256-row x 32-half W sub-tile (16 KiB), 2 loads/thread.
// stageA:   128-row x 32-half A sub-chunk (8 KiB), 1 load/thread.
// 64-half variants place the two 32-half sub-tiles back to back.
// ---------------------------------------------------------------------------
__device__ __forceinline__ void stage512(const _Float16* src, int K,
                                         char* ldsbase, int tid)
{
#pragma unroll
    for (int q = 0; q < 2; ++q) {
        const int s = q * 512 + tid;
        const int g = s >> 6, c2 = (s >> 4) & 3, r = (s & 15) ^ c2;
        const char* gp = (const char*)src + (size_t)(g * 16 + r) * (K * 2) + c2 * 16;
        char* lp = ldsbase + (q * 512 + (tid & ~63)) * 16;
        gload_lds16(gp, lp);
    }
}

__device__ __forceinline__ void stageA(const _Float16* src, int K,
                                       char* ldsbase, int tid)
{
    const int s = tid;
    const int g = s >> 6, c2 = (s >> 4) & 3, r = (s & 15) ^ c2;
    const char* gp = (const char*)src + (size_t)(g * 16 + r) * (K * 2) + c2 * 16;
    char* lp = ldsbase + (tid & ~63) * 16;
    gload_lds16(gp, lp);
}

// 64-half A chunk (16 KiB): 2 loads/thread
__device__ __forceinline__ void stageA64(const _Float16* src, int K,
                                         char* ldsbase, int tid)
{
    stageA(src,      K, ldsbase,        tid);
    stageA(src + 32, K, ldsbase + 8192, tid);
}

// 64-half W tile (32 KiB): 4 loads/thread
__device__ __forceinline__ void stageW64(const _Float16* src, int K,
                                         char* ldsbase, int tid)
{
    stage512(src,      K, ldsbase,         tid);
    stage512(src + 32, K, ldsbase + 16384, tid);
}

// 16 MFMAs over one 32-half sub-tile pair
__device__ __forceinline__ void do_step16(const char* ab, const char* bb,
                                          int wm, int wn, int lsw,
                                          f32x4 acc[4][4])
{
    half8_t af[4], wf[4];
#pragma unroll
    for (int i = 0; i < 4; ++i)
        af[i] = *(const half8_t*)(ab + (wm * 4 + i) * 1024 + lsw);
#pragma unroll
    for (int j = 0; j < 4; ++j)
        wf[j] = *(const half8_t*)(bb + (wn * 4 + j) * 1024 + lsw);
#pragma unroll
    for (int i = 0; i < 4; ++i)
#pragma unroll
        for (int j = 0; j < 4; ++j)
            acc[i][j] = __builtin_amdgcn_mfma_f32_16x16x32_f16(af[i], wf[j], acc[i][j], 0, 0, 0);
}

// 32 MFMAs: both 32-half sub-steps of a 64-half tile
__device__ __forceinline__ void do_step32(const char* ab, const char* bb,
                                          int wm, int wn, int lsw,
                                          f32x4 acc[4][4])
{
    do_step16(ab,        bb,         wm, wn, lsw, acc);
    do_step16(ab + 8192, bb + 16384, wm, wn, lsw, acc);
}

// bias+relu epilogue: scatter fp16 into XOR-swizzled fragment-order LDS
// (A-layout for the next phase; 32-half k-chunk stride 8192 B at R_=128).
__device__ __forceinline__ void epi_relu_lds(char* dst, const f32x4 acc[4][4],
                                             const float* __restrict__ bias,
                                             int wm, int wn, int lq, int lr)
{
#pragma unroll
    for (int j = 0; j < 4; ++j) {
        const int col = wn * 64 + j * 16 + lr;
        const float bv = bias[col];
        const int cc2 = (col & 31) >> 3;
        const int cpart = (col >> 5) * 8192 + cc2 * 256 + (col & 7) * 2;
#pragma unroll
        for (int i = 0; i < 4; ++i) {
#pragma unroll
            for (int rg = 0; rg < 4; ++rg) {
                const int row = wm * 64 + i * 16 + lq * 4 + rg;
                const float v = fmaxf(acc[i][j][rg] + bv, 0.f);
                *(_Float16*)(dst + cpart + (row >> 4) * 1024 +
                             (((row & 15) ^ cc2)) * 16) = (_Float16)v;
            }
        }
    }
}

// ---------------------------------------------------------------------------
// Fused MLP, BK=64: 36 steps of 32 MFMAs (vs 72x16 in r8), cross-phase
// W pre-staging so phase boundaries never expose a cold load.
// ---------------------------------------------------------------------------
__global__ __launch_bounds__(512, 2) void fused_mlp(
    const _Float16* __restrict__ xh,
    const _Float16* __restrict__ wsh, const float* __restrict__ bs,
    const _Float16* __restrict__ wmh, const float* __restrict__ bm,
    const _Float16* __restrict__ weh, const float* __restrict__ be,
    const _Float16* __restrict__ w2h, const float* __restrict__ b2,
    _Float16* __restrict__ bh)
{
    __shared__ __align__(16) char lds[LDS_BYTES];

    const int tid  = threadIdx.x;
    const int m0   = blockIdx.x * R_;
    const int lane = tid & 63;
    const int wave = tid >> 6;
    const int wm = wave >> 2;
    const int wn = wave & 3;
    const int lq = lane >> 4, lr = lane & 15;
    const int lsw = (lane ^ ((lane >> 4) & 3)) * 16;

    const _Float16* xrow = xh + (size_t)m0 * IN_;
    const f32x4 zero = {0.f, 0.f, 0.f, 0.f};

    // ---- P1: h1 = relu(xh @ Ws^T + bs), K=512, 8 steps of 64 ----
    {
        f32x4 acc[4][4];
#pragma unroll
        for (int i = 0; i < 4; ++i)
#pragma unroll
            for (int j = 0; j < 4; ++j) acc[i][j] = zero;

        stageA64(xrow, IN_, lds + H2S, tid);          // A0 -> slot0
        stageW64(wsh, IN_, lds + STG, tid);           // W0 even -> STG
        for (int s = 0; s < 7; ++s) {
            const int e = s + 1;
            stageA64(xrow + e * 64, IN_, lds + H2S + (e & 1) * 16384, tid);
            stageW64(wsh + e * 64, IN_, (e & 1) ? lds + H2S + 32768 : lds + STG, tid);
            VMCNT6(); SCHED0(); SBAR(); SCHED0();
            const char* ab = lds + H2S + (s & 1) * 16384;
            const char* bb = (s & 1) ? lds + H2S + 32768 : lds + STG;
            __builtin_amdgcn_s_setprio(1);
            do_step32(ab, bb, wm, wn, lsw, acc);
            __builtin_amdgcn_s_setprio(0);
            SCHED0(); SBAR(); SCHED0();
        }
        // s=7 (odd): pre-stage P2's W0 -> STG (P1 even tile consumed at s=6)
        stageW64(wmh, HYP_, lds + STG, tid);
        VMCNT4(); SCHED0(); SBAR(); SCHED0();
        __builtin_amdgcn_s_setprio(1);
        do_step32(lds + H2S + 16384, lds + H2S + 32768, wm, wn, lsw, acc);
        __builtin_amdgcn_s_setprio(0);
        __syncthreads();
        epi_relu_lds(lds + H1S, acc, bs, wm, wn, lq, lr);
        __syncthreads();
    }

    // ---- P2: h2 = relu(h1 @ Wm^T + bm), K=256, 4 steps ----
    {
        f32x4 acc[4][4];
#pragma unroll
        for (int i = 0; i < 4; ++i)
#pragma unroll
            for (int j = 0; j < 4; ++j) acc[i][j] = zero;

        for (int s = 0; s < 3; ++s) {
            const int e = s + 1;
            stageW64(wmh + e * 64, HYP_, (e & 1) ? lds + H2S : lds + STG, tid);
            VMCNT4(); SCHED0(); SBAR(); SCHED0();
            const char* ab = lds + H1S + s * 16384;
            const char* bb = (s & 1) ? lds + H2S : lds + STG;
            __builtin_amdgcn_s_setprio(1);
            do_step32(ab, bb, wm, wn, lsw, acc);
            __builtin_amdgcn_s_setprio(0);
            SCHED0(); SBAR(); SCHED0();
        }
        // s=3 (odd): pre-stage P3 half-0 fc W0 -> STG
        stageW64(weh, HYP_, lds + STG, tid);
        VMCNT4(); SCHED0(); SBAR(); SCHED0();
        __builtin_amdgcn_s_setprio(1);
        do_step32(lds + H1S + 49152, lds + H2S, wm, wn, lsw, acc);
        __builtin_amdgcn_s_setprio(0);
        __syncthreads();
        epi_relu_lds(lds + H2S, acc, bm, wm, wn, lq, lr);
        __syncthreads();
    }

    // ---- P3/P4 per 256-col half: fc (4 steps) + sig (8 steps) ----
#pragma unroll 1
    for (int half = 0; half < 2; ++half) {
        const int c0 = half * 256;
        const _Float16* wehh = weh + (size_t)c0 * HYP_;
        const _Float16* w2hh = w2h + (size_t)c0 * IN_;
        f32x4 accf[4][4], accs[4][4];
#pragma unroll
        for (int i = 0; i < 4; ++i)
#pragma unroll
            for (int j = 0; j < 4; ++j) { accf[i][j] = zero; accs[i][j] = zero; }

        // fc W0 already pre-staged in STG (by P2 s=3 / previous half's sig s=7)
        for (int s = 0; s < 3; ++s) {
            const int e = s + 1;
            stageW64(wehh + e * 64, HYP_, (e & 1) ? lds + H1S : lds + STG, tid);
            VMCNT4(); SCHED0(); SBAR(); SCHED0();
            const char* ab = lds + H2S + s * 16384;
            const char* bb = (s & 1) ? lds + H1S : lds + STG;
            __builtin_amdgcn_s_setprio(1);
            do_step32(ab, bb, wm, wn, lsw, accf);
            __builtin_amdgcn_s_setprio(0);
            SCHED0(); SBAR(); SCHED0();
        }
        // fc s=3 (odd): pre-stage sig tile 0 (A + W, 6 loads)
        stageA64(xrow, IN_, lds + H1S + 32768, tid);
        stageW64(w2hh, IN_, lds + STG, tid);
        VMCNT6(); SCHED0(); SBAR(); SCHED0();
        __builtin_amdgcn_s_setprio(1);
        do_step32(lds + H2S + 49152, lds + H1S, wm, wn, lsw, accf);
        __builtin_amdgcn_s_setprio(0);
        SCHED0(); SBAR(); SCHED0();

        // sig: 8 steps, K=512
        for (int s = 0; s < 7; ++s) {
            const int e = s + 1;
            stageA64(xrow + e * 64, IN_, lds + H1S + 32768 + (e & 1) * 16384, tid);
            stageW64(w2hh + e * 64, IN_, (e & 1) ? lds + H1S : lds + STG, tid);
            VMCNT6(); SCHED0(); SBAR(); SCHED0();
            const char* ab = lds + H1S + 32768 + (s & 1) * 16384;
            const char* bb = (s & 1) ? lds + H1S : lds + STG;
            __builtin_amdgcn_s_setprio(1);
            do_step32(ab, bb, wm, wn, lsw, accs);
            __builtin_amdgcn_s_setprio(0);
            SCHED0(); SBAR(); SCHED0();
        }
        // sig s=7 (odd): pre-stage next half's fc W0 (half 0 only)
        if (half == 0) {
            stageW64(weh + (size_t)256 * HYP_, HYP_, lds + STG, tid);
            VMCNT4();
        } else {
            VMCNT0();
        }
        SCHED0(); SBAR(); SCHED0();
        __builtin_amdgcn_s_setprio(1);
        do_step32(lds + H1S + 49152, lds + H1S, wm, wn, lsw, accs);
        __builtin_amdgcn_s_setprio(0);
        __syncthreads();

        // epilogue: bh(fp16) = (fc + be) * sigmoid(sig + b2)
#pragma unroll
        for (int j = 0; j < 4; ++j) {
            const int gcol = c0 + wn * 64 + j * 16 + lr;
            const float bev = be[gcol];
            const float b2v = b2[gcol];
#pragma unroll
            for (int i = 0; i < 4; ++i) {
#pragma unroll
                for (int rg = 0; rg < 4; ++rg) {
                    const int row = m0 + wm * 64 + i * 16 + lq * 4 + rg;
                    const float fc = accf[i][j][rg] + bev;
                    float sg = accs[i][j][rg] + b2v;
                    sg = 1.f / (1.f + __expf(-sg));
                    bh[(size_t)row * HID_ + gcol] = (_Float16)(fc * sg);
                }
            }
        }
        __syncthreads();   // protect H1S/STG before next half / exit
    }
}

// ---------------------------------------------------------------------------
// Segmented max-plus scan (proven r11): h' = relu(h + b) over a segment
// composes to h_out = max(h_in + S, D); (S,D) associative.
// ---------------------------------------------------------------------------
__global__ __launch_bounds__(256) void seg_reduce(const _Float16* __restrict__ bh,
                                                  float* __restrict__ Sarr,
                                                  float* __restrict__ Darr)
{
    const int G = blockIdx.x * 256 + threadIdx.x;
    const int r = G & 511;
    const int seg = (G >> 9) & 7;
    const int b = G >> 12;
    const int chain = b * 512 + r;
    const _Float16* bb = bh + (size_t)b * (T_ * HID_);
    const int t0 = seg * SEGL;

    float S = 0.f, D = -__builtin_inff();
#pragma unroll 8
    for (int u = 0; u < SEGL; ++u) {
        const int t = t0 + u;
        const float v = (float)bb[t * 512 + ((r + t) & 511)];
        S += v;
        D = fmaxf(D + v, 0.f);
    }
    Sarr[seg * NCH + chain] = S;
    Darr[seg * NCH + chain] = D;
}

__global__ __launch_bounds__(64) void carry_scan(const float* __restrict__ hidden,
                                                 const float* __restrict__ Sarr,
                                                 const float* __restrict__ Darr,
                                                 float* __restrict__ carry,
                                                 float* __restrict__ hlast)
{
    const int chain = blockIdx.x * 64 + threadIdx.x;
    const int b = chain >> 9, r = chain & 511;
    float c = hidden[b * 512 + ((r + 511) & 511)];
#pragma unroll
    for (int j = 0; j < NSEG; ++j) {
        carry[j * NCH + chain] = c;
        c = fmaxf(c + Sarr[j * NCH + chain], Darr[j * NCH + chain]);
    }
    hlast[b * 512 + ((r + 1023) & 511)] = c;
}

__global__ __launch_bounds__(256) void seg_apply(const _Float16* __restrict__ bh,
                                                 const float* __restrict__ carry,
                                                 float* __restrict__ out)
{
    const int G = blockIdx.x * 256 + threadIdx.x;
    const int r = G & 511;
    const int seg = (G >> 9) & 7;
    const int b = G >> 12;
    const int chain = b * 512 + r;
    const _Float16* bb = bh + (size_t)b * (T_ * HID_);
    float* ob = out + (size_t)b * (T_ * HID_);
    const int t0 = seg * SEGL;

    float c = carry[seg * NCH + chain];
#pragma unroll 8
    for (int u = 0; u < SEGL; ++u) {
        const int t = t0 + u;
        const int idx = t * 512 + ((r + t) & 511);
        c = fmaxf(c + (float)bb[idx], 0.f);
        ob[idx] = c;
    }
}

extern "C" void kernel_launch(void* const* d_in, const int* in_sizes, int n_in,
                              void* d_out, int out_size, void* d_ws, size_t ws_size,
                              hipStream_t stream)
{
    const float* x      = (const float*)d_in[0];  // [B,T,IN]
    const float* hidden = (const float*)d_in[1];  // [B,HID]
    const float* Ws     = (const float*)d_in[2];  // [HYP,IN]
    const float* bs     = (const float*)d_in[3];
    const float* Wm     = (const float*)d_in[4];  // [HYP,HYP]
    const float* bm     = (const float*)d_in[5];
    const float* We     = (const float*)d_in[6];  // [HID,HYP]
    const float* be     = (const float*)d_in[7];
    const float* W2     = (const float*)d_in[8];  // [HID,IN]
    const float* b2     = (const float*)d_in[9];

    float* outputs = (float*)d_out;                 // [B,T,HID]
    float* hlast   = outputs + (size_t)M_ * HID_;   // [B,HID]

    // xh (32 MB fp16) in the FRONT of d_out: read by fused_mlp, dead before
    // seg_apply overwrites the region (stream-ordered, fully rewritten).
    _Float16* xh = (_Float16*)d_out;                // [M,IN]

    // workspace: bh 32MB | weights 1.3MB | S,D,carry 1.5MB
    _Float16* bh   = (_Float16*)d_ws;
    _Float16* wsh  = bh + (size_t)M_ * HID_;        // [HYP,IN]
    _Float16* wmh  = wsh + HYP_ * IN_;              // [HYP,HYP]
    _Float16* weh  = wmh + HYP_ * HYP_;             // [HID,HYP]
    _Float16* w2h  = weh + HID_ * HYP_;             // [HID,IN]
    float*    Sarr = (float*)(w2h + HID_ * IN_);    // [NSEG, NCH]
    float*    Darr = Sarr + NSEG * NCH;             // [NSEG, NCH]
    float*    carr = Darr + NSEG * NCH;             // [NSEG, NCH]

    cvt_all<<<dim3(8480), 256, 0, stream>>>(x, xh, Ws, wsh, Wm, wmh, We, weh, W2, w2h);
    fused_mlp<<<dim3(M_ / R_), 512, 0, stream>>>(
        xh, wsh, bs, wmh, bm, weh, be, w2h, b2, bh);
    seg_reduce<<<dim3((NCH * NSEG) / 256), 256, 0, stream>>>(bh, Sarr, Darr);
    carry_scan<<<dim3(NCH / 64), 64, 0, stream>>>(hidden, Sarr, Darr, carr, hlast);
    seg_apply<<<dim3((NCH * NSEG) / 256), 256, 0, stream>>>(bh, carr, outputs);
}